// Round 11
// baseline (57.184 us; speedup 1.0000x reference)
//
#include <hip/hip_runtime.h>

#define B_ 32
#define N_ 256
#define C_ 512
#define O_ 512
#define S_ 512

#define KT  32                // weight k-tile (floats)
#define NKT (C_ / KT)         // 16 tiles
#define WST 40                // wt row stride in shorts: 80 B -> phase-20 bank spread

typedef __attribute__((ext_vector_type(8))) short short8;
typedef __attribute__((ext_vector_type(4))) float f32x4;

__device__ __forceinline__ short f2bf(float f) {
    union { float f; unsigned u; } v; v.f = f;
    unsigned r = v.u + 0x7fffu + ((v.u >> 16) & 1u);  // RNE (inputs finite)
    return (short)(r >> 16);
}
__device__ __forceinline__ float bf2f(short s) {
    union { unsigned u; float f; } v; v.u = ((unsigned)(unsigned short)s) << 16;
    return v.f;
}

// Non-draining barrier: LDS ordering only; weight loads stay in flight across it.
__device__ __forceinline__ void nd_barrier() {
    asm volatile("s_waitcnt lgkmcnt(0)" ::: "memory");
    __builtin_amdgcn_s_barrier();
}

// 512 blocks x 256 thr (4 waves): block = (n, o-half of 256 rows); 2 blocks/CU so
// one block's prologue/epilogue overlaps the other's weight stream. Chunked XCD
// swizzle keeps the two o-halves of one n on the same XCD (x re-stage hits L2).
__global__ __launch_bounds__(256, 2) void tml_kernel(const float* __restrict__ x,
                                                     const float* __restrict__ s,
                                                     const float* __restrict__ weight,
                                                     const float* __restrict__ bias,
                                                     const float* __restrict__ s_w,
                                                     const float* __restrict__ s_b,
                                                     float* __restrict__ out) {
    // chunked bijective XCD remap: 512 blocks, chunk = 64 per XCD
    const int h       = blockIdx.x;
    const int logical = (h & 7) * 64 + (h >> 3);
    const int n       = logical >> 1;
    const int half    = logical & 1;
    const int obase0  = half * 256;

    const int tid  = threadIdx.x;
    const int wv   = tid >> 6;    // 0..3
    const int lane = tid & 63;
    const int l16  = lane & 15;
    const int lk   = lane >> 4;

    __shared__ short xs[B_][C_ + 8];     // bf16 x (33.3 KB)
    __shared__ short wt[2][256][WST];    // bf16 weight k-tiles, dbuf (41 KB)
    __shared__ float sm_lds[B_];

    // staging map: 8 threads cover one row's 128 B k-slice; thread does rows i*32+srow
    const int srow = tid >> 3;   // 0..31
    const int scol = tid & 7;    // 16 B slot
    const float* wbase = weight + (size_t)n * (O_ * C_) + (size_t)obase0 * C_ + scol * 4;

    float4 rg0[8], rg1[8];
    // tile 0 in flight before smap + x staging
#pragma unroll
    for (int i = 0; i < 8; ++i)
        rg0[i] = *(const float4*)(wbase + (size_t)(i * 32 + srow) * C_);

    // ---- smap: sm_lds[b] = gain * dot(s[b,:], s_w[n,:]) + s_b[n]
    {
        const int b    = tid >> 3;       // 0..31
        const int slot = tid & 7;        // 8 threads per b
        const float* sp = s   + (size_t)b * S_ + slot * 64;
        const float* wp = s_w + (size_t)n * S_ + slot * 64;
        float sum = 0.f;
#pragma unroll
        for (int j = 0; j < 16; ++j) {
            float4 sv  = *(const float4*)(sp + 4 * j);
            float4 wv4 = *(const float4*)(wp + 4 * j);
            sum += sv.x * wv4.x + sv.y * wv4.y + sv.z * wv4.z + sv.w * wv4.w;
        }
        sum += __shfl_xor(sum, 1, 64);
        sum += __shfl_xor(sum, 2, 64);
        sum += __shfl_xor(sum, 4, 64);
        if (slot == 0) sm_lds[b] = sum * 0.04419417382415922f + s_b[n];
    }

    // ---- stage x[:, n, :] -> bf16 LDS (2nd same-n block hits XCD L2)
    const float* xn = x + (size_t)n * C_;
#pragma unroll
    for (int r = 0; r < 16; ++r) {
        int i  = r * 256 + tid;
        int b  = i >> 7;
        int c4 = (i & 127) << 2;
        const float4 v = *(const float4*)(xn + (size_t)b * (N_ * C_) + c4);
        short4 hh;
        hh.x = f2bf(v.x); hh.y = f2bf(v.y); hh.z = f2bf(v.z); hh.w = f2bf(v.w);
        *(short4*)&xs[b][c4] = hh;
    }

    f32x4 acc[4][2];
#pragma unroll
    for (int f = 0; f < 4; ++f)
#pragma unroll
        for (int m = 0; m < 2; ++m) acc[f][m] = (f32x4){0.f, 0.f, 0.f, 0.f};
    float ssq[4] = {0.f, 0.f, 0.f, 0.f};

    // STEP T: issue tile T+1 loads; commit tile T regs->LDS; nd-barrier; MFMA tile T.
    // dbuf race-free as proven in R9/R10 (lgkmcnt(0) at each barrier).
#define STEP(T, RCUR, RNXT, PB)                                                     \
    {                                                                               \
        if ((T) + 1 < NKT) {                                                        \
            _Pragma("unroll")                                                       \
            for (int i = 0; i < 8; ++i)                                             \
                RNXT[i] = *(const float4*)(wbase + (size_t)(i * 32 + srow) * C_     \
                                           + ((T) + 1) * KT);                       \
        }                                                                           \
        _Pragma("unroll")                                                           \
        for (int i = 0; i < 8; ++i) {                                               \
            short4 hv;                                                              \
            hv.x = f2bf(RCUR[i].x); hv.y = f2bf(RCUR[i].y);                         \
            hv.z = f2bf(RCUR[i].z); hv.w = f2bf(RCUR[i].w);                         \
            *(short4*)&wt[PB][i * 32 + srow][scol * 4] = hv;                        \
        }                                                                           \
        nd_barrier();                                                               \
        {                                                                           \
            const int co = lk * 8;                                                  \
            short8 a0 = *(const short8*)&xs[l16][(T) * KT + co];                    \
            short8 a1 = *(const short8*)&xs[16 + l16][(T) * KT + co];               \
            _Pragma("unroll")                                                       \
            for (int f = 0; f < 4; ++f) {                                           \
                short8 bf = *(const short8*)&wt[PB][wv * 64 + f * 16 + l16][co];    \
                _Pragma("unroll")                                                   \
                for (int j = 0; j < 8; ++j) {                                       \
                    float fv = bf2f(bf[j]); ssq[f] += fv * fv;                      \
                }                                                                   \
                acc[f][0] = __builtin_amdgcn_mfma_f32_16x16x32_bf16(a0, bf,         \
                                                          acc[f][0], 0, 0, 0);     \
                acc[f][1] = __builtin_amdgcn_mfma_f32_16x16x32_bf16(a1, bf,         \
                                                          acc[f][1], 0, 0, 0);     \
            }                                                                       \
        }                                                                           \
    }

    STEP(0,  rg0, rg1, 0)
    STEP(1,  rg1, rg0, 1)
    STEP(2,  rg0, rg1, 0)
    STEP(3,  rg1, rg0, 1)
    STEP(4,  rg0, rg1, 0)
    STEP(5,  rg1, rg0, 1)
    STEP(6,  rg0, rg1, 0)
    STEP(7,  rg1, rg0, 1)
    STEP(8,  rg0, rg1, 0)
    STEP(9,  rg1, rg0, 1)
    STEP(10, rg0, rg1, 0)
    STEP(11, rg1, rg0, 1)
    STEP(12, rg0, rg1, 0)
    STEP(13, rg1, rg0, 1)
    STEP(14, rg0, rg1, 0)
    STEP(15, rg1, rg0, 1)
#undef STEP

    // ssq partial per lk k-slice; reduce over lk (same o = l16 column)
#pragma unroll
    for (int f = 0; f < 4; ++f) {
        ssq[f] += __shfl_xor(ssq[f], 16, 64);
        ssq[f] += __shfl_xor(ssq[f], 32, 64);
    }

    // ---- epilogue. C/D layout: col = lane&15, row = (lane>>4)*4 + reg
#pragma unroll
    for (int f = 0; f < 4; ++f) {
        const int o    = obase0 + wv * 64 + f * 16 + l16;
        const float bv = bias[n * O_ + o];
        const float sq = ssq[f];
#pragma unroll
        for (int m = 0; m < 2; ++m) {
#pragma unroll
            for (int r = 0; r < 4; ++r) {
                const int brow  = m * 16 + lk * 4 + r;
                const float smv = sm_lds[brow];
                const float dec = rsqrtf(smv * smv * sq + 1e-8f);
                out[(size_t)brow * (N_ * O_) + n * O_ + o] =
                    acc[f][m][r] * smv * dec + bv;
            }
        }
    }
}

extern "C" void kernel_launch(void* const* d_in, const int* in_sizes, int n_in,
                              void* d_out, int out_size, void* d_ws, size_t ws_size,
                              hipStream_t stream) {
    const float* x      = (const float*)d_in[0];
    const float* s      = (const float*)d_in[1];
    const float* weight = (const float*)d_in[2];
    const float* bias   = (const float*)d_in[3];
    const float* s_w    = (const float*)d_in[4];
    const float* s_b    = (const float*)d_in[5];
    float* out = (float*)d_out;

    tml_kernel<<<N_ * 2, 256, 0, stream>>>(x, s, weight, bias, s_w, s_b, out);
}

// Round 12
// 54.621 us; speedup vs baseline: 1.0469x; 1.0469x over previous
//
#include <hip/hip_runtime.h>

#define B_ 32
#define N_ 256
#define C_ 512
#define O_ 512
#define S_ 512

#define KT  32                // weight k-tile (floats)
#define NKT (C_ / KT)         // 16 tiles
#define WST 40                // wt row stride in shorts: 80 B -> phase-20 bank spread

typedef __attribute__((ext_vector_type(8))) short short8;
typedef __attribute__((ext_vector_type(4))) float f32x4;

__device__ __forceinline__ short f2bf(float f) {
    union { float f; unsigned u; } v; v.f = f;
    unsigned r = v.u + 0x7fffu + ((v.u >> 16) & 1u);  // RNE (inputs finite)
    return (short)(r >> 16);
}
__device__ __forceinline__ float bf2f(short s) {
    union { unsigned u; float f; } v; v.u = ((unsigned)(unsigned short)s) << 16;
    return v.f;
}

// Non-draining barrier: LDS ordering only; weight loads stay in flight across it.
__device__ __forceinline__ void nd_barrier() {
    asm volatile("s_waitcnt lgkmcnt(0)" ::: "memory");
    __builtin_amdgcn_s_barrier();
}

// R10 structure (one block per n, 512 thr, 1 block/CU, single generation).
// ONLY change vs R10: both tiles 0 and 1 are loaded in the prologue, and
// STEP(T) re-issues tile T+2 into the just-committed register set — doubling
// the issue-to-wait distance (2 full steps > HBM latency) with no extra regs.
__global__ __launch_bounds__(512, 2) void tml_kernel(const float* __restrict__ x,
                                                     const float* __restrict__ s,
                                                     const float* __restrict__ weight,
                                                     const float* __restrict__ bias,
                                                     const float* __restrict__ s_w,
                                                     const float* __restrict__ s_b,
                                                     float* __restrict__ out) {
    const int n    = blockIdx.x;
    const int tid  = threadIdx.x;
    const int wv   = tid >> 6;    // 0..7
    const int lane = tid & 63;
    const int l16  = lane & 15;
    const int lk   = lane >> 4;

    __shared__ short xs[B_][C_ + 8];     // bf16 x (33.3 KB)
    __shared__ short wt[2][O_][WST];     // bf16 weight k-tiles, dbuf (80 KB)
    __shared__ float sm_lds[B_];

    // staging map: 8 threads cover one row's 128 B k-slice; thread does rows srow+64i
    const int srow = tid >> 3;   // 0..63
    const int scol = tid & 7;    // 16 B slot
    const float* wbase = weight + (size_t)n * (O_ * C_) + scol * 4;

    float4 rg0[8], rg1[8];
    // tiles 0 AND 1 in flight before smap + x staging
#pragma unroll
    for (int i = 0; i < 8; ++i)
        rg0[i] = *(const float4*)(wbase + (size_t)(i * 64 + srow) * C_);
#pragma unroll
    for (int i = 0; i < 8; ++i)
        rg1[i] = *(const float4*)(wbase + (size_t)(i * 64 + srow) * C_ + KT);

    // ---- smap (once per n): sm_lds[b] = gain * dot(s[b,:], s_w[n,:]) + s_b[n]
    {
        const int b    = tid >> 4;       // 0..31
        const int slot = tid & 15;       // 16 threads per b
        const float* sp = s   + (size_t)b * S_ + slot * 32;
        const float* wp = s_w + (size_t)n * S_ + slot * 32;
        float sum = 0.f;
#pragma unroll
        for (int j = 0; j < 8; ++j) {
            float4 sv  = *(const float4*)(sp + 4 * j);
            float4 wv4 = *(const float4*)(wp + 4 * j);
            sum += sv.x * wv4.x + sv.y * wv4.y + sv.z * wv4.z + sv.w * wv4.w;
        }
        sum += __shfl_xor(sum, 1, 64);
        sum += __shfl_xor(sum, 2, 64);
        sum += __shfl_xor(sum, 4, 64);
        sum += __shfl_xor(sum, 8, 64);
        if (slot == 0) sm_lds[b] = sum * 0.04419417382415922f + s_b[n];
    }

    // ---- stage x[:, n, :] -> bf16 LDS (once per n)
    const float* xn = x + (size_t)n * C_;
#pragma unroll
    for (int r = 0; r < 8; ++r) {
        int i  = r * 512 + tid;
        int b  = i >> 7;
        int c4 = (i & 127) << 2;
        const float4 v = *(const float4*)(xn + (size_t)b * (N_ * C_) + c4);
        short4 hh;
        hh.x = f2bf(v.x); hh.y = f2bf(v.y); hh.z = f2bf(v.z); hh.w = f2bf(v.w);
        *(short4*)&xs[b][c4] = hh;
    }

    f32x4 acc[4][2];
#pragma unroll
    for (int f = 0; f < 4; ++f)
#pragma unroll
        for (int m = 0; m < 2; ++m) acc[f][m] = (f32x4){0.f, 0.f, 0.f, 0.f};
    float ssq[4] = {0.f, 0.f, 0.f, 0.f};

    // STEP T: commit tile T (reads RC, waits its loads — issued 2 steps ago);
    // re-issue RC <- tile T+2; nd-barrier; MFMA tile T from wt[PB].
    // dbuf race-free: buffer PB rewritten only at T+2, after barrier T+1;
    // each wave's ds_reads of PB complete before it passes barrier T+1 (lgkmcnt 0).
#define STEP(T, RC, PB)                                                             \
    {                                                                               \
        _Pragma("unroll")                                                           \
        for (int i = 0; i < 8; ++i) {                                               \
            short4 hv;                                                              \
            hv.x = f2bf(RC[i].x); hv.y = f2bf(RC[i].y);                             \
            hv.z = f2bf(RC[i].z); hv.w = f2bf(RC[i].w);                             \
            *(short4*)&wt[PB][i * 64 + srow][scol * 4] = hv;                        \
        }                                                                           \
        if ((T) + 2 < NKT) {                                                        \
            _Pragma("unroll")                                                       \
            for (int i = 0; i < 8; ++i)                                             \
                RC[i] = *(const float4*)(wbase + (size_t)(i * 64 + srow) * C_       \
                                         + ((T) + 2) * KT);                         \
        }                                                                           \
        nd_barrier();                                                               \
        {                                                                           \
            const int co = lk * 8;                                                  \
            short8 a0 = *(const short8*)&xs[l16][(T) * KT + co];                    \
            short8 a1 = *(const short8*)&xs[16 + l16][(T) * KT + co];               \
            _Pragma("unroll")                                                       \
            for (int f = 0; f < 4; ++f) {                                           \
                short8 bf = *(const short8*)&wt[PB][wv * 64 + f * 16 + l16][co];    \
                _Pragma("unroll")                                                   \
                for (int j = 0; j < 8; ++j) {                                       \
                    float fv = bf2f(bf[j]); ssq[f] += fv * fv;                      \
                }                                                                   \
                acc[f][0] = __builtin_amdgcn_mfma_f32_16x16x32_bf16(a0, bf,         \
                                                          acc[f][0], 0, 0, 0);     \
                acc[f][1] = __builtin_amdgcn_mfma_f32_16x16x32_bf16(a1, bf,         \
                                                          acc[f][1], 0, 0, 0);     \
            }                                                                       \
        }                                                                           \
    }

    STEP(0,  rg0, 0)
    STEP(1,  rg1, 1)
    STEP(2,  rg0, 0)
    STEP(3,  rg1, 1)
    STEP(4,  rg0, 0)
    STEP(5,  rg1, 1)
    STEP(6,  rg0, 0)
    STEP(7,  rg1, 1)
    STEP(8,  rg0, 0)
    STEP(9,  rg1, 1)
    STEP(10, rg0, 0)
    STEP(11, rg1, 1)
    STEP(12, rg0, 0)
    STEP(13, rg1, 1)
    STEP(14, rg0, 0)
    STEP(15, rg1, 1)
#undef STEP

    // ssq partial per lk k-slice; reduce over lk (same o = l16 column)
#pragma unroll
    for (int f = 0; f < 4; ++f) {
        ssq[f] += __shfl_xor(ssq[f], 16, 64);
        ssq[f] += __shfl_xor(ssq[f], 32, 64);
    }

    // ---- epilogue. C/D layout: col = lane&15, row = (lane>>4)*4 + reg
#pragma unroll
    for (int f = 0; f < 4; ++f) {
        const int o    = wv * 64 + f * 16 + l16;
        const float bv = bias[n * O_ + o];
        const float sq = ssq[f];
#pragma unroll
        for (int m = 0; m < 2; ++m) {
#pragma unroll
            for (int r = 0; r < 4; ++r) {
                const int brow  = m * 16 + lk * 4 + r;
                const float smv = sm_lds[brow];
                const float dec = rsqrtf(smv * smv * sq + 1e-8f);
                out[(size_t)brow * (N_ * O_) + n * O_ + o] =
                    acc[f][m][r] * smv * dec + bv;
            }
        }
    }
}

extern "C" void kernel_launch(void* const* d_in, const int* in_sizes, int n_in,
                              void* d_out, int out_size, void* d_ws, size_t ws_size,
                              hipStream_t stream) {
    const float* x      = (const float*)d_in[0];
    const float* s      = (const float*)d_in[1];
    const float* weight = (const float*)d_in[2];
    const float* bias   = (const float*)d_in[3];
    const float* s_w    = (const float*)d_in[4];
    const float* s_b    = (const float*)d_in[5];
    float* out = (float*)d_out;

    tml_kernel<<<N_, 512, 0, stream>>>(x, s, weight, bias, s_w, s_b, out);
}

// Round 13
// 53.167 us; speedup vs baseline: 1.0755x; 1.0273x over previous
//
#include <hip/hip_runtime.h>

#define B_ 32
#define N_ 256
#define C_ 512
#define O_ 512
#define S_ 512

#define KT  32                // weight k-tile (floats)
#define NKT (C_ / KT)         // 16 tiles
#define WST 40                // wt row stride in shorts: 80 B -> phase-20 bank spread

typedef __attribute__((ext_vector_type(8))) short short8;
typedef __attribute__((ext_vector_type(4))) float f32x4;

__device__ __forceinline__ short f2bf(float f) {
    union { float f; unsigned u; } v; v.f = f;
    unsigned r = v.u + 0x7fffu + ((v.u >> 16) & 1u);  // RNE (inputs finite)
    return (short)(r >> 16);
}
__device__ __forceinline__ float bf2f(short s) {
    union { unsigned u; float f; } v; v.u = ((unsigned)(unsigned short)s) << 16;
    return v.f;
}

// Non-draining barrier: LDS ordering only; weight loads stay in flight across it.
__device__ __forceinline__ void nd_barrier() {
    asm volatile("s_waitcnt lgkmcnt(0)" ::: "memory");
    __builtin_amdgcn_s_barrier();
}

// R12 structure at 2x thread count: 256 blocks x 1024 thr (16 waves) = 1 block/CU,
// 4 waves/SIMD (vs 2). Isolates TLP: same dedup, same single generation, same
// barrier/pipeline scheme; per-thread commit work halves, twice the load agents.
// Wave w owns o-rows [w*32, w*32+32).
__global__ __launch_bounds__(1024, 1) void tml_kernel(const float* __restrict__ x,
                                                      const float* __restrict__ s,
                                                      const float* __restrict__ weight,
                                                      const float* __restrict__ bias,
                                                      const float* __restrict__ s_w,
                                                      const float* __restrict__ s_b,
                                                      float* __restrict__ out) {
    const int n    = blockIdx.x;
    const int tid  = threadIdx.x;
    const int wv   = tid >> 6;    // 0..15
    const int lane = tid & 63;
    const int l16  = lane & 15;
    const int lk   = lane >> 4;

    __shared__ short xs[B_][C_ + 8];     // bf16 x (33.3 KB)
    __shared__ short wt[2][O_][WST];     // bf16 weight k-tiles, dbuf (80 KB)
    __shared__ float sm_lds[B_];

    // staging map: 8 threads cover one row's 128 B k-slice; thread does rows srow+128i
    const int srow = tid >> 3;   // 0..127
    const int scol = tid & 7;    // 16 B slot
    const float* wbase = weight + (size_t)n * (O_ * C_) + scol * 4;

    float4 rg0[4], rg1[4];
    // tiles 0 AND 1 in flight before smap + x staging (depth-2 issue distance)
#pragma unroll
    for (int i = 0; i < 4; ++i)
        rg0[i] = *(const float4*)(wbase + (size_t)(i * 128 + srow) * C_);
#pragma unroll
    for (int i = 0; i < 4; ++i)
        rg1[i] = *(const float4*)(wbase + (size_t)(i * 128 + srow) * C_ + KT);

    // ---- smap (once per n): sm_lds[b] = gain * dot(s[b,:], s_w[n,:]) + s_b[n]
    {
        const int b    = tid >> 5;       // 0..31
        const int slot = tid & 31;       // 32 threads per b
        const float* sp = s   + (size_t)b * S_ + slot * 16;
        const float* wp = s_w + (size_t)n * S_ + slot * 16;
        float sum = 0.f;
#pragma unroll
        for (int j = 0; j < 4; ++j) {
            float4 sv  = *(const float4*)(sp + 4 * j);
            float4 wv4 = *(const float4*)(wp + 4 * j);
            sum += sv.x * wv4.x + sv.y * wv4.y + sv.z * wv4.z + sv.w * wv4.w;
        }
        sum += __shfl_xor(sum, 1, 64);
        sum += __shfl_xor(sum, 2, 64);
        sum += __shfl_xor(sum, 4, 64);
        sum += __shfl_xor(sum, 8, 64);
        sum += __shfl_xor(sum, 16, 64);
        if (slot == 0) sm_lds[b] = sum * 0.04419417382415922f + s_b[n];
    }

    // ---- stage x[:, n, :] -> bf16 LDS (once per n)
    const float* xn = x + (size_t)n * C_;
#pragma unroll
    for (int r = 0; r < 4; ++r) {
        int i  = r * 1024 + tid;
        int b  = i >> 7;
        int c4 = (i & 127) << 2;
        const float4 v = *(const float4*)(xn + (size_t)b * (N_ * C_) + c4);
        short4 hh;
        hh.x = f2bf(v.x); hh.y = f2bf(v.y); hh.z = f2bf(v.z); hh.w = f2bf(v.w);
        *(short4*)&xs[b][c4] = hh;
    }

    f32x4 acc[2][2];
#pragma unroll
    for (int f = 0; f < 2; ++f)
#pragma unroll
        for (int m = 0; m < 2; ++m) acc[f][m] = (f32x4){0.f, 0.f, 0.f, 0.f};
    float ssq[2] = {0.f, 0.f};

    // STEP T: commit tile T (waits loads issued 2 steps ago); re-issue RC <- tile
    // T+2; nd-barrier; MFMA tile T from wt[PB]. dbuf race-free as in R9-R12.
#define STEP(T, RC, PB)                                                             \
    {                                                                               \
        _Pragma("unroll")                                                           \
        for (int i = 0; i < 4; ++i) {                                               \
            short4 hv;                                                              \
            hv.x = f2bf(RC[i].x); hv.y = f2bf(RC[i].y);                             \
            hv.z = f2bf(RC[i].z); hv.w = f2bf(RC[i].w);                             \
            *(short4*)&wt[PB][i * 128 + srow][scol * 4] = hv;                       \
        }                                                                           \
        if ((T) + 2 < NKT) {                                                        \
            _Pragma("unroll")                                                       \
            for (int i = 0; i < 4; ++i)                                             \
                RC[i] = *(const float4*)(wbase + (size_t)(i * 128 + srow) * C_      \
                                         + ((T) + 2) * KT);                         \
        }                                                                           \
        nd_barrier();                                                               \
        {                                                                           \
            const int co = lk * 8;                                                  \
            short8 a0 = *(const short8*)&xs[l16][(T) * KT + co];                    \
            short8 a1 = *(const short8*)&xs[16 + l16][(T) * KT + co];               \
            _Pragma("unroll")                                                       \
            for (int f = 0; f < 2; ++f) {                                           \
                short8 bf = *(const short8*)&wt[PB][wv * 32 + f * 16 + l16][co];    \
                _Pragma("unroll")                                                   \
                for (int j = 0; j < 8; ++j) {                                       \
                    float fv = bf2f(bf[j]); ssq[f] += fv * fv;                      \
                }                                                                   \
                acc[f][0] = __builtin_amdgcn_mfma_f32_16x16x32_bf16(a0, bf,         \
                                                          acc[f][0], 0, 0, 0);     \
                acc[f][1] = __builtin_amdgcn_mfma_f32_16x16x32_bf16(a1, bf,         \
                                                          acc[f][1], 0, 0, 0);     \
            }                                                                       \
        }                                                                           \
    }

    STEP(0,  rg0, 0)
    STEP(1,  rg1, 1)
    STEP(2,  rg0, 0)
    STEP(3,  rg1, 1)
    STEP(4,  rg0, 0)
    STEP(5,  rg1, 1)
    STEP(6,  rg0, 0)
    STEP(7,  rg1, 1)
    STEP(8,  rg0, 0)
    STEP(9,  rg1, 1)
    STEP(10, rg0, 0)
    STEP(11, rg1, 1)
    STEP(12, rg0, 0)
    STEP(13, rg1, 1)
    STEP(14, rg0, 0)
    STEP(15, rg1, 1)
#undef STEP

    // ssq partial per lk k-slice; reduce over lk (same o = l16 column)
#pragma unroll
    for (int f = 0; f < 2; ++f) {
        ssq[f] += __shfl_xor(ssq[f], 16, 64);
        ssq[f] += __shfl_xor(ssq[f], 32, 64);
    }

    // ---- epilogue. C/D layout: col = lane&15, row = (lane>>4)*4 + reg
#pragma unroll
    for (int f = 0; f < 2; ++f) {
        const int o    = wv * 32 + f * 16 + l16;
        const float bv = bias[n * O_ + o];
        const float sq = ssq[f];
#pragma unroll
        for (int m = 0; m < 2; ++m) {
#pragma unroll
            for (int r = 0; r < 4; ++r) {
                const int brow  = m * 16 + lk * 4 + r;
                const float smv = sm_lds[brow];
                const float dec = rsqrtf(smv * smv * sq + 1e-8f);
                out[(size_t)brow * (N_ * O_) + n * O_ + o] =
                    acc[f][m][r] * smv * dec + bv;
            }
        }
    }
}

extern "C" void kernel_launch(void* const* d_in, const int* in_sizes, int n_in,
                              void* d_out, int out_size, void* d_ws, size_t ws_size,
                              hipStream_t stream) {
    const float* x      = (const float*)d_in[0];
    const float* s      = (const float*)d_in[1];
    const float* weight = (const float*)d_in[2];
    const float* bias   = (const float*)d_in[3];
    const float* s_w    = (const float*)d_in[4];
    const float* s_b    = (const float*)d_in[5];
    float* out = (float*)d_out;

    tml_kernel<<<N_, 1024, 0, stream>>>(x, s, weight, bias, s_w, s_b, out);
}